// Round 10
// baseline (7057.321 us; speedup 1.0000x reference)
//
#include <hip/hip_runtime.h>
#include <math.h>

#define NT 1024

// ---- per-sequence LDS layout (doubles) ----
#define D_YBUF 0
#define D_YCUR 64
#define D_KACC 128
#define D_H1   192    // 128
#define D_D1   320    // 128
#define D_H2   448    // 128
#define D_D2   576    // 128
#define D_FB   704    // 512
#define D_T3   1216   // 512
#define D_WM   1728   // 8*64
#define D_U1   2240   // 8*128
#define D_U2   3264   // 8*128
#define D_VSIG 4288   // 16*36
#define D_CMAT 4864   // 64
#define D_HID  4928   // 17*64
#define D_X0   6016   // 8
#define D_H2IC 6024   // 128 (ic scratch)
#define SEQ_STRIDE 6152
#define SMEM_BYTES (2 * SEQ_STRIDE * 8)

static __device__ __forceinline__ double lipswish_d(double z, double* d) {
    double s = 1.0 / (1.0 + exp(-z));
    *d = 0.909 * s * (1.0 + z * (1.0 - s));
    return 0.909 * z * s;
}

template<int CTRL>
static __device__ __forceinline__ double dpp_mov_d(double v) {
    long long xx = __double_as_longlong(v);
    int lo = (int)(xx & 0xffffffffLL);
    int hi = (int)(xx >> 32);
    lo = __builtin_amdgcn_update_dpp(0, lo, CTRL, 0xF, 0xF, false);
    hi = __builtin_amdgcn_update_dpp(0, hi, CTRL, 0xF, 0xF, false);
    return __longlong_as_double(((long long)hi << 32) | (unsigned int)lo);
}
// sum within quads (lanes xor 1, xor 2)
static __device__ __forceinline__ double red4(double v) {
    v += dpp_mov_d<0xB1>(v);   // quad_perm [1,0,3,2]
    v += dpp_mov_d<0x4E>(v);   // quad_perm [2,3,0,1]
    return v;
}

extern "C" __global__ void __launch_bounds__(NT, 1)
ncde_solve(const float* __restrict__ x,
           const float* __restrict__ ic_w1, const float* __restrict__ ic_b1,
           const float* __restrict__ ic_w2, const float* __restrict__ ic_b2,
           const float* __restrict__ ic_w3, const float* __restrict__ ic_b3,
           const float* __restrict__ vf_w1, const float* __restrict__ vf_b1,
           const float* __restrict__ vf_w2, const float* __restrict__ vf_b2,
           const float* __restrict__ vf_w3, const float* __restrict__ vf_b3,
           const float* __restrict__ ro_w,  const float* __restrict__ ro_b,
           float* __restrict__ out, int B)
{
    extern __shared__ double smd[];

    const int t = threadIdx.x;
    const int seq = t >> 9;
    const int tp = t & 511;
    const int gseq0 = blockIdx.x * 2 + seq;
    const int gseq = gseq0 < B ? gseq0 : B - 1;
    const bool live = gseq0 < B;
    const int SB = seq * SEQ_STRIDE;
    const float* xb = x + (size_t)gseq * (257 * 8);

    const int o = tp >> 2, p = tp & 3;     // L1/L2/U1/U2 mapping
    const int aT = tp >> 6;                // WM/T3 tangent = wave-within-seq

    // ---- per-thread weights: W1 row o cols [16p,16p+16) f32; W2 row o cols [32p,32p+32) f64 ----
    float w1f[16];
    {
        const float4* s4 = reinterpret_cast<const float4*>(vf_w1 + o * 64 + 16 * p);
        #pragma unroll
        for (int jj = 0; jj < 4; ++jj) {
            float4 v = s4[jj];
            w1f[4 * jj] = v.x; w1f[4 * jj + 1] = v.y;
            w1f[4 * jj + 2] = v.z; w1f[4 * jj + 3] = v.w;
        }
    }
    double w2d[32];
    {
        const float4* s4 = reinterpret_cast<const float4*>(vf_w2 + o * 128 + 32 * p);
        #pragma unroll
        for (int jj = 0; jj < 8; ++jj) {
            float4 v = s4[jj];
            w2d[4 * jj] = v.x; w2d[4 * jj + 1] = v.y;
            w2d[4 * jj + 2] = v.z; w2d[4 * jj + 3] = v.w;
        }
    }
    const float4* w3r = reinterpret_cast<const float4*>(vf_w3 + (size_t)tp * 128);
    const double b1o = (double)vf_b1[o];
    const double b2o = (double)vf_b2[o];
    const double b3t = (double)vf_b3[tp];

    // ==== init: X0 + logsigs (per seq) ====
    if (tp < 8) smd[SB + D_X0 + tp] = (double)xb[tp];
    if (tp < 16) {
        const float* xr = xb + tp * 16 * 8;
        double cum[8], area[28], prev[8];
        #pragma unroll
        for (int i = 0; i < 8; ++i) { cum[i] = 0.0; prev[i] = (double)xr[i]; }
        #pragma unroll
        for (int u = 0; u < 28; ++u) area[u] = 0.0;
        for (int k = 1; k <= 16; ++k) {
            double dx[8];
            #pragma unroll
            for (int i = 0; i < 8; ++i) {
                double c = (double)xr[k * 8 + i];
                dx[i] = c - prev[i];
                prev[i] = c;
            }
            #pragma unroll
            for (int i = 0; i < 7; ++i) {
                #pragma unroll
                for (int j = i + 1; j < 8; ++j) {
                    int u = 7 * i - (i * (i - 1)) / 2 + (j - i - 1);
                    area[u] += 0.5 * (cum[i] * dx[j] - cum[j] * dx[i]);
                }
            }
            #pragma unroll
            for (int i = 0; i < 8; ++i) cum[i] += dx[i];
        }
        #pragma unroll
        for (int i = 0; i < 8; ++i) smd[SB + D_VSIG + tp * 36 + i] = cum[i];
        #pragma unroll
        for (int u = 0; u < 28; ++u) smd[SB + D_VSIG + tp * 36 + 8 + u] = area[u];
    }
    __syncthreads();

    // ==== ic MLP (per seq; scratch FB=h1, H2IC=h2) ====
    if (tp < 128) {
        double acc = (double)ic_b1[tp];
        #pragma unroll
        for (int e = 0; e < 8; ++e) acc += (double)ic_w1[tp * 8 + e] * smd[SB + D_X0 + e];
        double d;
        smd[SB + D_FB + tp] = lipswish_d(acc, &d);
    }
    __syncthreads();
    if (tp < 128) {
        const float4* wr = reinterpret_cast<const float4*>(ic_w2 + tp * 128);
        double a0 = 0.0, a1 = 0.0, a2 = 0.0, a3 = 0.0;
        #pragma unroll
        for (int k = 0; k < 32; ++k) {
            float4 wv = wr[k];
            double2 h0 = *reinterpret_cast<const double2*>(&smd[SB + D_FB + 4 * k]);
            double2 h1 = *reinterpret_cast<const double2*>(&smd[SB + D_FB + 4 * k + 2]);
            a0 += (double)wv.x * h0.x; a1 += (double)wv.y * h0.y;
            a2 += (double)wv.z * h1.x; a3 += (double)wv.w * h1.y;
        }
        double d;
        smd[SB + D_H2IC + tp] = lipswish_d((double)ic_b2[tp] + (a0 + a2) + (a1 + a3), &d);
    }
    __syncthreads();
    if (tp < 64) {
        const float4* wr = reinterpret_cast<const float4*>(ic_w3 + tp * 128);
        double a0 = 0.0, a1 = 0.0, a2 = 0.0, a3 = 0.0;
        #pragma unroll
        for (int k = 0; k < 32; ++k) {
            float4 wv = wr[k];
            double2 h0 = *reinterpret_cast<const double2*>(&smd[SB + D_H2IC + 4 * k]);
            double2 h1 = *reinterpret_cast<const double2*>(&smd[SB + D_H2IC + 4 * k + 2]);
            a0 += (double)wv.x * h0.x; a1 += (double)wv.y * h0.y;
            a2 += (double)wv.z * h1.x; a3 += (double)wv.w * h1.y;
        }
        double y0 = (double)ic_b3[tp] + (a0 + a2) + (a1 + a3);
        smd[SB + D_YCUR + tp] = y0;
        smd[SB + D_YBUF + tp] = y0;
        smd[SB + D_HID + tp]  = y0;
        int a = tp >> 3, bb = tp & 7;
        double cv = 0.0;
        if (a != bb) {
            int i = a < bb ? a : bb;
            int j = a < bb ? bb : a;
            int pidx = 7 * i - (i * (i - 1)) / 2 + (j - i - 1);
            double vv = smd[SB + D_VSIG + 8 + pidx];
            cv = (a > bb) ? vv : -vv;
        }
        smd[SB + D_CMAT + tp] = cv;
    }
    __syncthreads();

    // ==== RK4 scan ====
    for (int w = 0; w < 16; ++w) {
        for (int stage = 0; stage < 4; ++stage) {
            // ---- P1: L1 ----
            {
                double acc = 0.0;
                #pragma unroll
                for (int k = 0; k < 16; k += 2) {
                    double2 yv = *reinterpret_cast<const double2*>(&smd[SB + D_YBUF + 16 * p + k]);
                    acc += (double)w1f[k] * yv.x + (double)w1f[k + 1] * yv.y;
                }
                acc = red4(acc);
                if (p == 0) {
                    double d;
                    smd[SB + D_H1 + o] = lipswish_d(acc + b1o, &d);
                    smd[SB + D_D1 + o] = d;
                }
            }
            __syncthreads();
            // ---- P2: L2 ----
            {
                double acc = 0.0;
                #pragma unroll
                for (int k = 0; k < 32; k += 2) {
                    double2 hv = *reinterpret_cast<const double2*>(&smd[SB + D_H1 + 32 * p + k]);
                    acc += w2d[k] * hv.x + w2d[k + 1] * hv.y;
                }
                acc = red4(acc);
                if (p == 0) {
                    double d;
                    smd[SB + D_H2 + o] = lipswish_d(acc + b2o, &d);
                    smd[SB + D_D2 + o] = d;
                }
            }
            __syncthreads();
            // ---- P3: L3 (w3 row from global, full 128-dot) ----
            double F_reg;
            {
                double a0 = 0.0, a1 = 0.0, a2 = 0.0, a3 = 0.0;
                #pragma unroll
                for (int k = 0; k < 32; ++k) {
                    float4 wv = w3r[k];
                    double2 h0 = *reinterpret_cast<const double2*>(&smd[SB + D_H2 + 4 * k]);
                    double2 h1 = *reinterpret_cast<const double2*>(&smd[SB + D_H2 + 4 * k + 2]);
                    a0 += (double)wv.x * h0.x; a1 += (double)wv.y * h0.y;
                    a2 += (double)wv.z * h1.x; a3 += (double)wv.w * h1.y;
                }
                F_reg = tanh(b3t + (a0 + a2) + (a1 + a3));
                smd[SB + D_FB + tp] = F_reg;
            }
            __syncthreads();
            // ---- P4: WM ----
            {
                int e = tp & 63;
                double s = 0.0;
                #pragma unroll
                for (int bb = 0; bb < 8; ++bb)
                    s += smd[SB + D_CMAT + aT * 8 + bb] * smd[SB + D_FB + bb * 64 + e];
                smd[SB + D_WM + aT * 64 + e] = s;
            }
            __syncthreads();
            // ---- P5: U1 (loop tangents) ----
            {
                double d1o = smd[SB + D_D1 + o];
                #pragma unroll
                for (int a = 0; a < 8; ++a) {
                    double acc = 0.0;
                    #pragma unroll
                    for (int k = 0; k < 16; k += 2) {
                        double2 mv = *reinterpret_cast<const double2*>(&smd[SB + D_WM + a * 64 + 16 * p + k]);
                        acc += (double)w1f[k] * mv.x + (double)w1f[k + 1] * mv.y;
                    }
                    acc = red4(acc);
                    if (p == 0) smd[SB + D_U1 + a * 128 + o] = acc * d1o;
                }
            }
            __syncthreads();
            // ---- P6: U2 (loop tangents) ----
            {
                double d2o = smd[SB + D_D2 + o];
                #pragma unroll
                for (int a = 0; a < 8; ++a) {
                    double acc = 0.0;
                    #pragma unroll
                    for (int k = 0; k < 32; k += 2) {
                        double2 uv = *reinterpret_cast<const double2*>(&smd[SB + D_U1 + a * 128 + 32 * p + k]);
                        acc += w2d[k] * uv.x + w2d[k + 1] * uv.y;
                    }
                    acc = red4(acc);
                    if (p == 0) smd[SB + D_U2 + a * 128 + o] = acc * d2o;
                }
            }
            __syncthreads();
            // ---- P7: T3 (w3 row from global, tangent aT) ----
            {
                double a0 = 0.0, a1 = 0.0, a2 = 0.0, a3 = 0.0;
                #pragma unroll
                for (int k = 0; k < 32; ++k) {
                    float4 wv = w3r[k];
                    double2 u0 = *reinterpret_cast<const double2*>(&smd[SB + D_U2 + aT * 128 + 4 * k]);
                    double2 u1 = *reinterpret_cast<const double2*>(&smd[SB + D_U2 + aT * 128 + 4 * k + 2]);
                    a0 += (double)wv.x * u0.x; a1 += (double)wv.y * u0.y;
                    a2 += (double)wv.z * u1.x; a3 += (double)wv.w * u1.y;
                }
                double va = smd[SB + D_VSIG + w * 36 + aT];
                smd[SB + D_T3 + tp] = va * F_reg + (1.0 - F_reg * F_reg) * ((a0 + a2) + (a1 + a3));
            }
            __syncthreads();
            // ---- P8: combine + RK4 glue (+ next CMAT) ----
            if (tp < 64) {
                double g = 0.0;
                #pragma unroll
                for (int a = 0; a < 8; ++a) g += smd[SB + D_T3 + a * 64 + tp];
                double y = smd[SB + D_YCUR + tp];
                if (stage == 0)      { smd[SB + D_KACC + tp] = g;        smd[SB + D_YBUF + tp] = y + 0.5 * g; }
                else if (stage == 1) { smd[SB + D_KACC + tp] += 2.0 * g; smd[SB + D_YBUF + tp] = y + 0.5 * g; }
                else if (stage == 2) { smd[SB + D_KACC + tp] += 2.0 * g; smd[SB + D_YBUF + tp] = y + g; }
                else {
                    double yn = y + (smd[SB + D_KACC + tp] + g) * (1.0 / 6.0);
                    smd[SB + D_YCUR + tp] = yn;
                    smd[SB + D_YBUF + tp] = yn;
                    smd[SB + D_HID + (w + 1) * 64 + tp] = yn;
                }
            } else if (tp < 128 && stage == 3 && w < 15) {
                int idx = tp - 64;
                int a = idx >> 3, bb = idx & 7;
                double cv = 0.0;
                if (a != bb) {
                    int i = a < bb ? a : bb;
                    int j = a < bb ? bb : a;
                    int pidx = 7 * i - (i * (i - 1)) / 2 + (j - i - 1);
                    double vv = smd[SB + D_VSIG + (w + 1) * 36 + 8 + pidx];
                    cv = (a > bb) ? vv : -vv;
                }
                smd[SB + D_CMAT + idx] = cv;
            }
            __syncthreads();
        }
    }

    // ==== readout ====
    if (live) {
        for (int idx = tp; idx < 544; idx += 512) {
            int s = idx >> 5, oo = idx & 31;
            double acc = (double)ro_b[oo];
            const float* wr = ro_w + oo * 64;
            const double* hr = &smd[SB + D_HID + s * 64];
            #pragma unroll
            for (int d = 0; d < 64; ++d) acc += (double)wr[d] * hr[d];
            out[(size_t)gseq * 544 + idx] = (float)acc;
        }
    }
}

extern "C" void kernel_launch(void* const* d_in, const int* in_sizes, int n_in,
                              void* d_out, int out_size, void* d_ws, size_t ws_size,
                              hipStream_t stream) {
    const float* x     = (const float*)d_in[0];
    const float* ic_w1 = (const float*)d_in[1];
    const float* ic_b1 = (const float*)d_in[2];
    const float* ic_w2 = (const float*)d_in[3];
    const float* ic_b2 = (const float*)d_in[4];
    const float* ic_w3 = (const float*)d_in[5];
    const float* ic_b3 = (const float*)d_in[6];
    const float* vf_w1 = (const float*)d_in[7];
    const float* vf_b1 = (const float*)d_in[8];
    const float* vf_w2 = (const float*)d_in[9];
    const float* vf_b2 = (const float*)d_in[10];
    const float* vf_w3 = (const float*)d_in[11];
    const float* vf_b3 = (const float*)d_in[12];
    const float* ro_w  = (const float*)d_in[13];
    const float* ro_b  = (const float*)d_in[14];
    float* out = (float*)d_out;

    int B = in_sizes[0] / (257 * 8);
    int grid = (B + 1) / 2;
    hipFuncSetAttribute(reinterpret_cast<const void*>(ncde_solve),
                        hipFuncAttributeMaxDynamicSharedMemorySize, SMEM_BYTES);
    hipLaunchKernelGGL(ncde_solve, dim3(grid), dim3(NT), SMEM_BYTES, stream,
                       x, ic_w1, ic_b1, ic_w2, ic_b2, ic_w3, ic_b3,
                       vf_w1, vf_b1, vf_w2, vf_b2, vf_w3, vf_b3, ro_w, ro_b, out, B);
}

// Round 11
// 1252.252 us; speedup vs baseline: 5.6357x; 5.6357x over previous
//
#include <hip/hip_runtime.h>
#include <math.h>

#define NT 1024

// ---- f64 LDS region (doubles), padded layouts ----
// pad8(j)=j+2*(j>>3)  pad16(j)=j+2*(j>>4)
#define D_YBUF 0      // 80
#define D_YCUR 80     // 64
#define D_KACC 144    // 64
#define D_H1   208    // 144 (pad16)
#define D_D1   352    // 128
#define D_H2   480    // 144 (pad16)
#define D_D2   624    // 128
#define D_FB   752    // 512 (also ic h1 scratch)
#define D_T3   1264   // 512 (also ic h2 scratch)
#define D_VSIG 1776   // 16*36
#define D_CMAT 2352   // 64
#define D_HID  2416   // 17*64
#define D_X0   3504   // 8
#define D_TOTAL 3512

// ---- f32 LDS region (tangent intermediates) ----
#define FWM 0         // 8*68
#define FU1 544       // 8*132
#define FU2 1600      // 8*132
#define F_TOTAL 2656

static __device__ __forceinline__ double lipswish_d(double z, double* d) {
    double s = 1.0 / (1.0 + exp(-z));
    *d = 0.909 * s * (1.0 + z * (1.0 - s));
    return 0.909 * z * s;
}

template<int CTRL>
static __device__ __forceinline__ double dpp_mov_d(double v) {
    long long xx = __double_as_longlong(v);
    int lo = (int)(xx & 0xffffffffLL);
    int hi = (int)(xx >> 32);
    lo = __builtin_amdgcn_update_dpp(0, lo, CTRL, 0xF, 0xF, false);
    hi = __builtin_amdgcn_update_dpp(0, hi, CTRL, 0xF, 0xF, false);
    return __longlong_as_double(((long long)hi << 32) | (unsigned int)lo);
}
template<int CTRL>
static __device__ __forceinline__ float dpp_mov_f(float v) {
    int xx = __builtin_amdgcn_update_dpp(0, __float_as_int(v), CTRL, 0xF, 0xF, false);
    return __int_as_float(xx);
}
static __device__ __forceinline__ double red8d(double v) {
    v += dpp_mov_d<0xB1>(v);
    v += dpp_mov_d<0x4E>(v);
    v += dpp_mov_d<0x141>(v);
    return v;
}
static __device__ __forceinline__ double red2d(double v) {
    return v + dpp_mov_d<0xB1>(v);
}
static __device__ __forceinline__ float red8f(float v) {
    v += dpp_mov_f<0xB1>(v);
    v += dpp_mov_f<0x4E>(v);
    v += dpp_mov_f<0x141>(v);
    return v;
}

extern "C" __global__ void __launch_bounds__(NT, 1)
ncde_solve(const float* __restrict__ x,
           const float* __restrict__ ic_w1, const float* __restrict__ ic_b1,
           const float* __restrict__ ic_w2, const float* __restrict__ ic_b2,
           const float* __restrict__ ic_w3, const float* __restrict__ ic_b3,
           const float* __restrict__ vf_w1, const float* __restrict__ vf_b1,
           const float* __restrict__ vf_w2, const float* __restrict__ vf_b2,
           const float* __restrict__ vf_w3, const float* __restrict__ vf_b3,
           const float* __restrict__ ro_w,  const float* __restrict__ ro_b,
           float* __restrict__ out)
{
    __shared__ double smd[D_TOTAL];
    __shared__ __align__(16) float smf[F_TOTAL];

    const int t = threadIdx.x;
    const int b = blockIdx.x;
    const float* xb = x + (size_t)b * (257 * 8);

    const int o = t >> 3, p = t & 7;        // L1/L2/U1/U2 mapping
    const int row3 = t >> 1, q = t & 1;     // L3/T3 mapping
    const int aT = t >> 7;                  // tangent for T3/WM

    // ---- weights in f32 registers ----
    float w1f[8];
    {
        const float4* s4 = reinterpret_cast<const float4*>(vf_w1 + o * 64 + 8 * p);
        float4 v0 = s4[0], v1 = s4[1];
        w1f[0] = v0.x; w1f[1] = v0.y; w1f[2] = v0.z; w1f[3] = v0.w;
        w1f[4] = v1.x; w1f[5] = v1.y; w1f[6] = v1.z; w1f[7] = v1.w;
    }
    float w2f[16];
    {
        const float4* s4 = reinterpret_cast<const float4*>(vf_w2 + o * 128 + 16 * p);
        #pragma unroll
        for (int jj = 0; jj < 4; ++jj) {
            float4 v = s4[jj];
            w2f[4 * jj] = v.x; w2f[4 * jj + 1] = v.y;
            w2f[4 * jj + 2] = v.z; w2f[4 * jj + 3] = v.w;
        }
    }
    float w3f[64];
    {
        const float4* s4 = reinterpret_cast<const float4*>(vf_w3 + (size_t)row3 * 128 + 64 * q);
        #pragma unroll
        for (int jj = 0; jj < 16; ++jj) {
            float4 v = s4[jj];
            w3f[4 * jj] = v.x; w3f[4 * jj + 1] = v.y;
            w3f[4 * jj + 2] = v.z; w3f[4 * jj + 3] = v.w;
        }
    }
    const double b1o = (double)vf_b1[o];
    const double b2o = (double)vf_b2[o];
    const double b3r = (double)vf_b3[row3];

    // ==== init: X0 + logsigs ====
    if (t < 8) smd[D_X0 + t] = (double)xb[t];
    if (t < 16) {
        const float* xr = xb + t * 16 * 8;
        double cum[8], area[28], prev[8];
        #pragma unroll
        for (int i = 0; i < 8; ++i) { cum[i] = 0.0; prev[i] = (double)xr[i]; }
        #pragma unroll
        for (int u = 0; u < 28; ++u) area[u] = 0.0;
        for (int k = 1; k <= 16; ++k) {
            double dx[8];
            #pragma unroll
            for (int i = 0; i < 8; ++i) {
                double c = (double)xr[k * 8 + i];
                dx[i] = c - prev[i];
                prev[i] = c;
            }
            #pragma unroll
            for (int i = 0; i < 7; ++i) {
                #pragma unroll
                for (int j = i + 1; j < 8; ++j) {
                    int u = 7 * i - (i * (i - 1)) / 2 + (j - i - 1);
                    area[u] += 0.5 * (cum[i] * dx[j] - cum[j] * dx[i]);
                }
            }
            #pragma unroll
            for (int i = 0; i < 8; ++i) cum[i] += dx[i];
        }
        #pragma unroll
        for (int i = 0; i < 8; ++i) smd[D_VSIG + t * 36 + i] = cum[i];
        #pragma unroll
        for (int u = 0; u < 28; ++u) smd[D_VSIG + t * 36 + 8 + u] = area[u];
    }
    __syncthreads();

    // ==== ic MLP (scratch: FB=h1ic, T3=h2ic) ====
    if (t < 128) {
        double acc = (double)ic_b1[t];
        #pragma unroll
        for (int e = 0; e < 8; ++e) acc += (double)ic_w1[t * 8 + e] * smd[D_X0 + e];
        double d;
        smd[D_FB + t] = lipswish_d(acc, &d);
    }
    __syncthreads();
    if (t < 128) {
        const float4* wr = reinterpret_cast<const float4*>(ic_w2 + t * 128);
        double a0 = 0.0, a1 = 0.0, a2 = 0.0, a3 = 0.0;
        #pragma unroll
        for (int k = 0; k < 32; ++k) {
            float4 wv = wr[k];
            double2 h0 = *reinterpret_cast<const double2*>(&smd[D_FB + 4 * k]);
            double2 h1 = *reinterpret_cast<const double2*>(&smd[D_FB + 4 * k + 2]);
            a0 += (double)wv.x * h0.x; a1 += (double)wv.y * h0.y;
            a2 += (double)wv.z * h1.x; a3 += (double)wv.w * h1.y;
        }
        double d;
        smd[D_T3 + t] = lipswish_d((double)ic_b2[t] + (a0 + a2) + (a1 + a3), &d);
    }
    __syncthreads();
    if (t < 64) {
        const float4* wr = reinterpret_cast<const float4*>(ic_w3 + t * 128);
        double a0 = 0.0, a1 = 0.0, a2 = 0.0, a3 = 0.0;
        #pragma unroll
        for (int k = 0; k < 32; ++k) {
            float4 wv = wr[k];
            double2 h0 = *reinterpret_cast<const double2*>(&smd[D_T3 + 4 * k]);
            double2 h1 = *reinterpret_cast<const double2*>(&smd[D_T3 + 4 * k + 2]);
            a0 += (double)wv.x * h0.x; a1 += (double)wv.y * h0.y;
            a2 += (double)wv.z * h1.x; a3 += (double)wv.w * h1.y;
        }
        double y0 = (double)ic_b3[t] + (a0 + a2) + (a1 + a3);
        smd[D_YCUR + t] = y0;
        smd[D_YBUF + t + 2 * (t >> 3)] = y0;
        smd[D_HID + t]  = y0;
        int a = t >> 3, bb = t & 7;
        double cv = 0.0;
        if (a != bb) {
            int i = a < bb ? a : bb;
            int j = a < bb ? bb : a;
            int pidx = 7 * i - (i * (i - 1)) / 2 + (j - i - 1);
            double vv = smd[D_VSIG + 8 + pidx];
            cv = (a > bb) ? vv : -vv;
        }
        smd[D_CMAT + t] = cv;
    }
    __syncthreads();

    // ==== RK4 scan ====
    for (int w = 0; w < 16; ++w) {
        for (int stage = 0; stage < 4; ++stage) {
            // ---- P1: L1 (f64, reg f32 weights) ----
            {
                double acc = 0.0;
                #pragma unroll
                for (int k = 0; k < 8; k += 2) {
                    double2 yv = *reinterpret_cast<const double2*>(&smd[D_YBUF + 10 * p + k]);
                    acc += (double)w1f[k] * yv.x + (double)w1f[k + 1] * yv.y;
                }
                acc = red8d(acc);
                if (p == 0) {
                    double d;
                    smd[D_H1 + o + 2 * (o >> 4)] = lipswish_d(acc + b1o, &d);
                    smd[D_D1 + o] = d;
                }
            }
            __syncthreads();
            // ---- P2: L2 (f64) ----
            {
                double acc = 0.0;
                #pragma unroll
                for (int k = 0; k < 16; k += 2) {
                    double2 hv = *reinterpret_cast<const double2*>(&smd[D_H1 + 18 * p + k]);
                    acc += (double)w2f[k] * hv.x + (double)w2f[k + 1] * hv.y;
                }
                acc = red8d(acc);
                if (p == 0) {
                    double d;
                    smd[D_H2 + o + 2 * (o >> 4)] = lipswish_d(acc + b2o, &d);
                    smd[D_D2 + o] = d;
                }
            }
            __syncthreads();
            // ---- P3: L3 f64: F = tanh(W3 h2 + b3) ----
            double F_reg = 0.0;
            {
                double acc = 0.0;
                #pragma unroll
                for (int k = 0; k < 64; k += 2) {
                    double2 hv = *reinterpret_cast<const double2*>(&smd[D_H2 + 72 * q + k + 2 * (k >> 4)]);
                    acc += (double)w3f[k] * hv.x + (double)w3f[k + 1] * hv.y;
                }
                acc = red2d(acc);
                if (q == 0) {
                    F_reg = tanh(acc + b3r);
                    smd[D_FB + row3] = F_reg;
                }
            }
            __syncthreads();
            // ---- P4: WM (f64 math, f32 store) ----
            {
                int kw = t & 1, ew = (t >> 1) & 63;
                double s = 0.0;
                #pragma unroll
                for (int i = 0; i < 4; ++i) {
                    int bb = 4 * kw + i;
                    s += smd[D_CMAT + aT * 8 + bb] * smd[D_FB + bb * 64 + ew];
                }
                s = red2d(s);
                if (kw == 0) smf[FWM + aT * 68 + ew] = (float)s;
            }
            __syncthreads();
            // ---- P5: U1 f32 (batched over tangents) ----
            {
                float d1f = (float)smd[D_D1 + o];
                #pragma unroll
                for (int a = 0; a < 8; ++a) {
                    float acc = 0.0f;
                    #pragma unroll
                    for (int jj = 0; jj < 2; ++jj) {
                        int jr = (jj + p) & 1;
                        float4 mv = *reinterpret_cast<const float4*>(&smf[FWM + a * 68 + 8 * p + 4 * jr]);
                        acc += w1f[4 * jr] * mv.x + w1f[4 * jr + 1] * mv.y
                             + w1f[4 * jr + 2] * mv.z + w1f[4 * jr + 3] * mv.w;
                    }
                    acc = red8f(acc);
                    if (p == 0) smf[FU1 + a * 132 + o] = acc * d1f;
                }
            }
            __syncthreads();
            // ---- P6: U2 f32 (batched over tangents) ----
            {
                float d2f = (float)smd[D_D2 + o];
                #pragma unroll
                for (int a = 0; a < 8; ++a) {
                    float acc = 0.0f;
                    #pragma unroll
                    for (int jj = 0; jj < 4; ++jj) {
                        int jr = (jj + p) & 3;
                        float4 uv = *reinterpret_cast<const float4*>(&smf[FU1 + a * 132 + 16 * p + 4 * jr]);
                        acc += w2f[4 * jr] * uv.x + w2f[4 * jr + 1] * uv.y
                             + w2f[4 * jr + 2] * uv.z + w2f[4 * jr + 3] * uv.w;
                    }
                    acc = red8f(acc);
                    if (p == 0) smf[FU2 + a * 132 + o] = acc * d2f;
                }
            }
            __syncthreads();
            // ---- P7: T3 (f32 dot, f64 finish) ----
            {
                float acc = 0.0f;
                #pragma unroll
                for (int jj = 0; jj < 16; ++jj) {
                    float4 uv = *reinterpret_cast<const float4*>(&smf[FU2 + aT * 132 + 64 * q + 4 * jj]);
                    acc += w3f[4 * jj] * uv.x + w3f[4 * jj + 1] * uv.y
                         + w3f[4 * jj + 2] * uv.z + w3f[4 * jj + 3] * uv.w;
                }
                acc += dpp_mov_f<0xB1>(acc);
                if (q == 0) {
                    double va = smd[D_VSIG + w * 36 + aT];
                    smd[D_T3 + row3] = va * F_reg + (1.0 - F_reg * F_reg) * (double)acc;
                }
            }
            __syncthreads();
            // ---- P8: combine + RK4 glue (+ next CMAT) ----
            if (t < 64) {
                double g = 0.0;
                #pragma unroll
                for (int a = 0; a < 8; ++a) g += smd[D_T3 + a * 64 + t];
                double y = smd[D_YCUR + t];
                int yp = D_YBUF + t + 2 * (t >> 3);
                if (stage == 0)      { smd[D_KACC + t] = g;        smd[yp] = y + 0.5 * g; }
                else if (stage == 1) { smd[D_KACC + t] += 2.0 * g; smd[yp] = y + 0.5 * g; }
                else if (stage == 2) { smd[D_KACC + t] += 2.0 * g; smd[yp] = y + g; }
                else {
                    double yn = y + (smd[D_KACC + t] + g) * (1.0 / 6.0);
                    smd[D_YCUR + t] = yn;
                    smd[yp] = yn;
                    smd[D_HID + (w + 1) * 64 + t] = yn;
                }
            } else if (t < 128 && stage == 3 && w < 15) {
                int idx = t - 64;
                int a = idx >> 3, bb = idx & 7;
                double cv = 0.0;
                if (a != bb) {
                    int i = a < bb ? a : bb;
                    int j = a < bb ? bb : a;
                    int pidx = 7 * i - (i * (i - 1)) / 2 + (j - i - 1);
                    double vv = smd[D_VSIG + (w + 1) * 36 + 8 + pidx];
                    cv = (a > bb) ? vv : -vv;
                }
                smd[D_CMAT + idx] = cv;
            }
            __syncthreads();
        }
    }

    // ==== readout ====
    for (int idx = t; idx < 544; idx += NT) {
        int s = idx >> 5, oo = idx & 31;
        double acc = (double)ro_b[oo];
        const float* wr = ro_w + oo * 64;
        const double* hr = &smd[D_HID + s * 64];
        #pragma unroll
        for (int d = 0; d < 64; ++d) acc += (double)wr[d] * hr[d];
        out[(size_t)b * 544 + idx] = (float)acc;
    }
}

extern "C" void kernel_launch(void* const* d_in, const int* in_sizes, int n_in,
                              void* d_out, int out_size, void* d_ws, size_t ws_size,
                              hipStream_t stream) {
    const float* x     = (const float*)d_in[0];
    const float* ic_w1 = (const float*)d_in[1];
    const float* ic_b1 = (const float*)d_in[2];
    const float* ic_w2 = (const float*)d_in[3];
    const float* ic_b2 = (const float*)d_in[4];
    const float* ic_w3 = (const float*)d_in[5];
    const float* ic_b3 = (const float*)d_in[6];
    const float* vf_w1 = (const float*)d_in[7];
    const float* vf_b1 = (const float*)d_in[8];
    const float* vf_w2 = (const float*)d_in[9];
    const float* vf_b2 = (const float*)d_in[10];
    const float* vf_w3 = (const float*)d_in[11];
    const float* vf_b3 = (const float*)d_in[12];
    const float* ro_w  = (const float*)d_in[13];
    const float* ro_b  = (const float*)d_in[14];
    float* out = (float*)d_out;

    int B = in_sizes[0] / (257 * 8);
    hipLaunchKernelGGL(ncde_solve, dim3(B), dim3(NT), 0, stream,
                       x, ic_w1, ic_b1, ic_w2, ic_b2, ic_w3, ic_b3,
                       vf_w1, vf_b1, vf_w2, vf_b2, vf_w3, vf_b3, ro_w, ro_b, out);
}

// Round 13
// 904.931 us; speedup vs baseline: 7.7987x; 1.3838x over previous
//
#include <hip/hip_runtime.h>
#include <math.h>

#define NT 1024

// ---- f64 LDS region (doubles), padded layouts ----
// pad8(j)=j+2*(j>>3)  pad16(j)=j+2*(j>>4)
#define D_YBUF 0      // 80
#define D_YCUR 80     // 64
#define D_KACC 144    // 64
#define D_H1   208    // 144 (pad16)
#define D_D1   352    // 128
#define D_H2   480    // 144 (pad16)
#define D_D2   624    // 128
#define D_FB   752    // 512 (also ic h1 scratch)
#define D_T3   1264   // 512 (also ic h2 scratch)
#define D_VSIG 1776   // 16*36
#define D_CMAT 2352   // 64
#define D_HID  2416   // 17*64
#define D_X0   3504   // 8
#define D_TOTAL 3512

// ---- f32 LDS region (tangent intermediates), exact conflict-free pads ----
// WM[a][e] at a*96  + e + 4*(e>>3)   (slice stride 12)
// U1[a][r] at a*160 + r + 4*(r>>4)   (slice stride 20)
// U2[a][r] at a*160 + r + 4*(r>>4)
#define FWM 0         // 768
#define FU1 768       // 1280
#define FU2 2048      // 1280
#define F_TOTAL 3328

static __device__ __forceinline__ double lipswish_d(double z, double* d) {
    double s = 1.0 / (1.0 + exp(-z));
    *d = 0.909 * s * (1.0 + z * (1.0 - s));
    return 0.909 * z * s;
}

template<int CTRL>
static __device__ __forceinline__ double dpp_mov_d(double v) {
    long long xx = __double_as_longlong(v);
    int lo = (int)(xx & 0xffffffffLL);
    int hi = (int)(xx >> 32);
    lo = __builtin_amdgcn_update_dpp(0, lo, CTRL, 0xF, 0xF, false);
    hi = __builtin_amdgcn_update_dpp(0, hi, CTRL, 0xF, 0xF, false);
    return __longlong_as_double(((long long)hi << 32) | (unsigned int)lo);
}
template<int CTRL>
static __device__ __forceinline__ float dpp_mov_f(float v) {
    int xx = __builtin_amdgcn_update_dpp(0, __float_as_int(v), CTRL, 0xF, 0xF, false);
    return __int_as_float(xx);
}
static __device__ __forceinline__ double red8d(double v) {
    v += dpp_mov_d<0xB1>(v);
    v += dpp_mov_d<0x4E>(v);
    v += dpp_mov_d<0x141>(v);
    return v;
}
static __device__ __forceinline__ double red4d(double v) {
    v += dpp_mov_d<0xB1>(v);
    v += dpp_mov_d<0x4E>(v);
    return v;
}
static __device__ __forceinline__ double red2d(double v) {
    return v + dpp_mov_d<0xB1>(v);
}
static __device__ __forceinline__ float red8f(float v) {
    v += dpp_mov_f<0xB1>(v);
    v += dpp_mov_f<0x4E>(v);
    v += dpp_mov_f<0x141>(v);
    return v;
}
static __device__ __forceinline__ float red4f(float v) {
    v += dpp_mov_f<0xB1>(v);
    v += dpp_mov_f<0x4E>(v);
    return v;
}

extern "C" __global__ void __launch_bounds__(NT, 1)
ncde_solve(const float* __restrict__ x,
           const float* __restrict__ ic_w1, const float* __restrict__ ic_b1,
           const float* __restrict__ ic_w2, const float* __restrict__ ic_b2,
           const float* __restrict__ ic_w3, const float* __restrict__ ic_b3,
           const float* __restrict__ vf_w1, const float* __restrict__ vf_b1,
           const float* __restrict__ vf_w2, const float* __restrict__ vf_b2,
           const float* __restrict__ vf_w3, const float* __restrict__ vf_b3,
           const float* __restrict__ ro_w,  const float* __restrict__ ro_b,
           float* __restrict__ out)
{
    __shared__ double smd[D_TOTAL];
    __shared__ __align__(16) float smf[F_TOTAL];

    const int t = threadIdx.x;
    const int b = blockIdx.x;
    const float* xb = x + (size_t)b * (257 * 8);

    const int o = t >> 3, p = t & 7;        // P1/P2/P5/P6 mapping
    const int m = t >> 2, q = t & 3;        // P3/P7: rows 2m,2m+1, K-slice q
    const int aT = t >> 7;                  // tangent block (= (2m)>>6)

    // ---- weights in f32 registers ----
    float w1f[8];
    {
        const float4* s4 = reinterpret_cast<const float4*>(vf_w1 + o * 64 + 8 * p);
        float4 v0 = s4[0], v1 = s4[1];
        w1f[0] = v0.x; w1f[1] = v0.y; w1f[2] = v0.z; w1f[3] = v0.w;
        w1f[4] = v1.x; w1f[5] = v1.y; w1f[6] = v1.z; w1f[7] = v1.w;
    }
    float w2f[16];
    {
        const float4* s4 = reinterpret_cast<const float4*>(vf_w2 + o * 128 + 16 * p);
        #pragma unroll
        for (int jj = 0; jj < 4; ++jj) {
            float4 v = s4[jj];
            w2f[4 * jj] = v.x; w2f[4 * jj + 1] = v.y;
            w2f[4 * jj + 2] = v.z; w2f[4 * jj + 3] = v.w;
        }
    }
    float w3a[32], w3b[32];
    {
        const float4* sa = reinterpret_cast<const float4*>(vf_w3 + (size_t)(2 * m) * 128 + 32 * q);
        const float4* sb = reinterpret_cast<const float4*>(vf_w3 + (size_t)(2 * m + 1) * 128 + 32 * q);
        #pragma unroll
        for (int jj = 0; jj < 8; ++jj) {
            float4 va = sa[jj], vb = sb[jj];
            w3a[4 * jj] = va.x; w3a[4 * jj + 1] = va.y; w3a[4 * jj + 2] = va.z; w3a[4 * jj + 3] = va.w;
            w3b[4 * jj] = vb.x; w3b[4 * jj + 1] = vb.y; w3b[4 * jj + 2] = vb.z; w3b[4 * jj + 3] = vb.w;
        }
    }
    const double b1o = (double)vf_b1[o];
    const double b2o = (double)vf_b2[o];
    const double b3a = (double)vf_b3[2 * m];
    const double b3b = (double)vf_b3[2 * m + 1];

    // ==== init: X0 + logsigs ====
    if (t < 8) smd[D_X0 + t] = (double)xb[t];
    if (t < 16) {
        const float* xr = xb + t * 16 * 8;
        double cum[8], area[28], prev[8];
        #pragma unroll
        for (int i = 0; i < 8; ++i) { cum[i] = 0.0; prev[i] = (double)xr[i]; }
        #pragma unroll
        for (int u = 0; u < 28; ++u) area[u] = 0.0;
        for (int k = 1; k <= 16; ++k) {
            double dx[8];
            #pragma unroll
            for (int i = 0; i < 8; ++i) {
                double c = (double)xr[k * 8 + i];
                dx[i] = c - prev[i];
                prev[i] = c;
            }
            #pragma unroll
            for (int i = 0; i < 7; ++i) {
                #pragma unroll
                for (int j = i + 1; j < 8; ++j) {
                    int u = 7 * i - (i * (i - 1)) / 2 + (j - i - 1);
                    area[u] += 0.5 * (cum[i] * dx[j] - cum[j] * dx[i]);
                }
            }
            #pragma unroll
            for (int i = 0; i < 8; ++i) cum[i] += dx[i];
        }
        #pragma unroll
        for (int i = 0; i < 8; ++i) smd[D_VSIG + t * 36 + i] = cum[i];
        #pragma unroll
        for (int u = 0; u < 28; ++u) smd[D_VSIG + t * 36 + 8 + u] = area[u];
    }
    __syncthreads();

    // ==== ic MLP (scratch: FB=h1ic, T3=h2ic) ====
    if (t < 128) {
        double acc = (double)ic_b1[t];
        #pragma unroll
        for (int e = 0; e < 8; ++e) acc += (double)ic_w1[t * 8 + e] * smd[D_X0 + e];
        double d;
        smd[D_FB + t] = lipswish_d(acc, &d);
    }
    __syncthreads();
    if (t < 128) {
        const float4* wr = reinterpret_cast<const float4*>(ic_w2 + t * 128);
        double a0 = 0.0, a1 = 0.0, a2 = 0.0, a3 = 0.0;
        #pragma unroll
        for (int k = 0; k < 32; ++k) {
            float4 wv = wr[k];
            double2 h0 = *reinterpret_cast<const double2*>(&smd[D_FB + 4 * k]);
            double2 h1 = *reinterpret_cast<const double2*>(&smd[D_FB + 4 * k + 2]);
            a0 += (double)wv.x * h0.x; a1 += (double)wv.y * h0.y;
            a2 += (double)wv.z * h1.x; a3 += (double)wv.w * h1.y;
        }
        double d;
        smd[D_T3 + t] = lipswish_d((double)ic_b2[t] + (a0 + a2) + (a1 + a3), &d);
    }
    __syncthreads();
    if (t < 64) {
        const float4* wr = reinterpret_cast<const float4*>(ic_w3 + t * 128);
        double a0 = 0.0, a1 = 0.0, a2 = 0.0, a3 = 0.0;
        #pragma unroll
        for (int k = 0; k < 32; ++k) {
            float4 wv = wr[k];
            double2 h0 = *reinterpret_cast<const double2*>(&smd[D_T3 + 4 * k]);
            double2 h1 = *reinterpret_cast<const double2*>(&smd[D_T3 + 4 * k + 2]);
            a0 += (double)wv.x * h0.x; a1 += (double)wv.y * h0.y;
            a2 += (double)wv.z * h1.x; a3 += (double)wv.w * h1.y;
        }
        double y0 = (double)ic_b3[t] + (a0 + a2) + (a1 + a3);
        smd[D_YCUR + t] = y0;
        smd[D_YBUF + t + 2 * (t >> 3)] = y0;
        smd[D_HID + t]  = y0;
        int a = t >> 3, bb = t & 7;
        double cv = 0.0;
        if (a != bb) {
            int i = a < bb ? a : bb;
            int j = a < bb ? bb : a;
            int pidx = 7 * i - (i * (i - 1)) / 2 + (j - i - 1);
            double vv = smd[D_VSIG + 8 + pidx];
            cv = (a > bb) ? vv : -vv;
        }
        smd[D_CMAT + t] = cv;
    }
    __syncthreads();

    // ==== RK4 scan ====
    for (int w = 0; w < 16; ++w) {
        for (int stage = 0; stage < 4; ++stage) {
            // ---- P1: L1 (f64) ----
            {
                double acc = 0.0;
                #pragma unroll
                for (int k = 0; k < 8; k += 2) {
                    double2 yv = *reinterpret_cast<const double2*>(&smd[D_YBUF + 10 * p + k]);
                    acc += (double)w1f[k] * yv.x + (double)w1f[k + 1] * yv.y;
                }
                acc = red8d(acc);
                if (p == 0) {
                    double d;
                    smd[D_H1 + o + 2 * (o >> 4)] = lipswish_d(acc + b1o, &d);
                    smd[D_D1 + o] = d;
                }
            }
            __syncthreads();
            // ---- P2: L2 (f64) ----
            {
                double acc = 0.0;
                #pragma unroll
                for (int k = 0; k < 16; k += 2) {
                    double2 hv = *reinterpret_cast<const double2*>(&smd[D_H1 + 18 * p + k]);
                    acc += (double)w2f[k] * hv.x + (double)w2f[k + 1] * hv.y;
                }
                acc = red8d(acc);
                if (p == 0) {
                    double d;
                    smd[D_H2 + o + 2 * (o >> 4)] = lipswish_d(acc + b2o, &d);
                    smd[D_D2 + o] = d;
                }
            }
            __syncthreads();
            // ---- P3: L3 f64, dual-row q4 split ----
            double F0 = 0.0, F1 = 0.0;
            {
                double a0 = 0.0, a1 = 0.0;
                #pragma unroll
                for (int k = 0; k < 32; k += 2) {
                    double2 hv = *reinterpret_cast<const double2*>(&smd[D_H2 + 36 * q + k + 2 * (k >> 4)]);
                    a0 += (double)w3a[k] * hv.x + (double)w3a[k + 1] * hv.y;
                    a1 += (double)w3b[k] * hv.x + (double)w3b[k + 1] * hv.y;
                }
                a0 = red4d(a0);
                a1 = red4d(a1);
                if (q == 0) {
                    F0 = tanh(a0 + b3a);
                    F1 = tanh(a1 + b3b);
                    double2 fv; fv.x = F0; fv.y = F1;
                    *reinterpret_cast<double2*>(&smd[D_FB + 2 * m]) = fv;
                }
            }
            __syncthreads();
            // ---- P4: WM (f64 math, padded f32 store) ----
            {
                int kw = t & 1, ew = (t >> 1) & 63, a4 = t >> 7;
                double s = 0.0;
                #pragma unroll
                for (int i = 0; i < 4; ++i) {
                    int bb = 4 * kw + i;
                    s += smd[D_CMAT + a4 * 8 + bb] * smd[D_FB + bb * 64 + ew];
                }
                s = red2d(s);
                if (kw == 0) smf[FWM + a4 * 96 + ew + 4 * (ew >> 3)] = (float)s;
            }
            __syncthreads();
            // ---- P5: U1 f32 (batched over tangents) ----
            {
                float d1f = (float)smd[D_D1 + o];
                #pragma unroll
                for (int a = 0; a < 8; ++a) {
                    float acc = 0.0f;
                    #pragma unroll
                    for (int jj = 0; jj < 2; ++jj) {
                        float4 mv = *reinterpret_cast<const float4*>(&smf[FWM + a * 96 + 12 * p + 4 * jj]);
                        acc += w1f[4 * jj] * mv.x + w1f[4 * jj + 1] * mv.y
                             + w1f[4 * jj + 2] * mv.z + w1f[4 * jj + 3] * mv.w;
                    }
                    acc = red8f(acc);
                    if (p == 0) smf[FU1 + a * 160 + o + 4 * (o >> 4)] = acc * d1f;
                }
            }
            __syncthreads();
            // ---- P6: U2 f32 (batched over tangents) ----
            {
                float d2f = (float)smd[D_D2 + o];
                #pragma unroll
                for (int a = 0; a < 8; ++a) {
                    float acc = 0.0f;
                    #pragma unroll
                    for (int jj = 0; jj < 4; ++jj) {
                        float4 uv = *reinterpret_cast<const float4*>(&smf[FU1 + a * 160 + 20 * p + 4 * jj]);
                        acc += w2f[4 * jj] * uv.x + w2f[4 * jj + 1] * uv.y
                             + w2f[4 * jj + 2] * uv.z + w2f[4 * jj + 3] * uv.w;
                    }
                    acc = red8f(acc);
                    if (p == 0) smf[FU2 + a * 160 + o + 4 * (o >> 4)] = acc * d2f;
                }
            }
            __syncthreads();
            // ---- P7: T3, dual-row q4 split (f32 dot, f64 finish) ----
            // NOTE: FU2 slice has a 4-float pad after element 16 -> add 4*(jj>>2)
            {
                float a0 = 0.0f, a1 = 0.0f;
                #pragma unroll
                for (int jj = 0; jj < 8; ++jj) {
                    float4 uv = *reinterpret_cast<const float4*>(
                        &smf[FU2 + aT * 160 + 40 * q + 4 * jj + 4 * (jj >> 2)]);
                    a0 += w3a[4 * jj] * uv.x + w3a[4 * jj + 1] * uv.y
                        + w3a[4 * jj + 2] * uv.z + w3a[4 * jj + 3] * uv.w;
                    a1 += w3b[4 * jj] * uv.x + w3b[4 * jj + 1] * uv.y
                        + w3b[4 * jj + 2] * uv.z + w3b[4 * jj + 3] * uv.w;
                }
                a0 = red4f(a0);
                a1 = red4f(a1);
                if (q == 0) {
                    double va = smd[D_VSIG + w * 36 + aT];
                    double2 tv;
                    tv.x = va * F0 + (1.0 - F0 * F0) * (double)a0;
                    tv.y = va * F1 + (1.0 - F1 * F1) * (double)a1;
                    *reinterpret_cast<double2*>(&smd[D_T3 + 2 * m]) = tv;
                }
            }
            __syncthreads();
            // ---- P8: combine + RK4 glue (+ next CMAT) ----
            if (t < 64) {
                double g = 0.0;
                #pragma unroll
                for (int a = 0; a < 8; ++a) g += smd[D_T3 + a * 64 + t];
                double y = smd[D_YCUR + t];
                int yp = D_YBUF + t + 2 * (t >> 3);
                if (stage == 0)      { smd[D_KACC + t] = g;        smd[yp] = y + 0.5 * g; }
                else if (stage == 1) { smd[D_KACC + t] += 2.0 * g; smd[yp] = y + 0.5 * g; }
                else if (stage == 2) { smd[D_KACC + t] += 2.0 * g; smd[yp] = y + g; }
                else {
                    double yn = y + (smd[D_KACC + t] + g) * (1.0 / 6.0);
                    smd[D_YCUR + t] = yn;
                    smd[yp] = yn;
                    smd[D_HID + (w + 1) * 64 + t] = yn;
                }
            } else if (t < 128 && stage == 3 && w < 15) {
                int idx = t - 64;
                int a = idx >> 3, bb = idx & 7;
                double cv = 0.0;
                if (a != bb) {
                    int i = a < bb ? a : bb;
                    int j = a < bb ? bb : a;
                    int pidx = 7 * i - (i * (i - 1)) / 2 + (j - i - 1);
                    double vv = smd[D_VSIG + (w + 1) * 36 + 8 + pidx];
                    cv = (a > bb) ? vv : -vv;
                }
                smd[D_CMAT + idx] = cv;
            }
            __syncthreads();
        }
    }

    // ==== readout ====
    for (int idx = t; idx < 544; idx += NT) {
        int s = idx >> 5, oo = idx & 31;
        double acc = (double)ro_b[oo];
        const float* wr = ro_w + oo * 64;
        const double* hr = &smd[D_HID + s * 64];
        #pragma unroll
        for (int d = 0; d < 64; ++d) acc += (double)wr[d] * hr[d];
        out[(size_t)b * 544 + idx] = (float)acc;
    }
}

extern "C" void kernel_launch(void* const* d_in, const int* in_sizes, int n_in,
                              void* d_out, int out_size, void* d_ws, size_t ws_size,
                              hipStream_t stream) {
    const float* x     = (const float*)d_in[0];
    const float* ic_w1 = (const float*)d_in[1];
    const float* ic_b1 = (const float*)d_in[2];
    const float* ic_w2 = (const float*)d_in[3];
    const float* ic_b2 = (const float*)d_in[4];
    const float* ic_w3 = (const float*)d_in[5];
    const float* ic_b3 = (const float*)d_in[6];
    const float* vf_w1 = (const float*)d_in[7];
    const float* vf_b1 = (const float*)d_in[8];
    const float* vf_w2 = (const float*)d_in[9];
    const float* vf_b2 = (const float*)d_in[10];
    const float* vf_w3 = (const float*)d_in[11];
    const float* vf_b3 = (const float*)d_in[12];
    const float* ro_w  = (const float*)d_in[13];
    const float* ro_b  = (const float*)d_in[14];
    float* out = (float*)d_out;

    int B = in_sizes[0] / (257 * 8);
    hipLaunchKernelGGL(ncde_solve, dim3(B), dim3(NT), 0, stream,
                       x, ic_w1, ic_b1, ic_w2, ic_b2, ic_w3, ic_b3,
                       vf_w1, vf_b1, vf_w2, vf_b2, vf_w3, vf_b3, ro_w, ro_b, out);
}

// Round 14
// 639.433 us; speedup vs baseline: 11.0368x; 1.4152x over previous
//
#include <hip/hip_runtime.h>
#include <math.h>

#define NT 1024

// ---- f64 LDS (doubles) ----
#define D_YCUR 0      // 64
#define D_KACC 64     // 64
#define D_T3   128    // 512 (also ic scratch: h1ic at +0..127, h2ic at +128..255)
#define D_VSIG 640    // 16*36
#define D_HID  1216   // 17*64
#define D_X0   2304   // 8
#define D_TOTAL 2312

// ---- f32 LDS ----
// pads: YB e+4*(e>>3) (stride 12/8); H1,H2,U-slices r+4*(r>>4) (stride 20/16)
#define F_YB 0        // 96
#define F_H1 96       // 160
#define F_D1 256      // 128
#define F_H2 384      // 160
#define F_D2 544      // 128
#define F_FB 672      // 512 linear
#define F_WM 1184     // 512 linear [8][64]
#define F_U1 1696     // 1280: a*160 + r + 4*(r>>4)
#define F_U2 2976     // 1280
#define F_CM 4256     // 64
#define F_TOTAL 4320

static __device__ __forceinline__ double lipswish_d(double z, double* d) {
    double s = 1.0 / (1.0 + exp(-z));
    *d = 0.909 * s * (1.0 + z * (1.0 - s));
    return 0.909 * z * s;
}
static __device__ __forceinline__ float lipswish_f(float z, float* d) {
    float s = 1.0f / (1.0f + expf(-z));
    *d = 0.909f * s * (1.0f + z * (1.0f - s));
    return 0.909f * z * s;
}

template<int CTRL>
static __device__ __forceinline__ float dpp_mov_f(float v) {
    int xx = __builtin_amdgcn_update_dpp(0, __float_as_int(v), CTRL, 0xF, 0xF, false);
    return __int_as_float(xx);
}
static __device__ __forceinline__ float red8f(float v) {
    v += dpp_mov_f<0xB1>(v);
    v += dpp_mov_f<0x4E>(v);
    v += dpp_mov_f<0x141>(v);
    return v;
}
static __device__ __forceinline__ float red16f(float v) {
    v += dpp_mov_f<0xB1>(v);
    v += dpp_mov_f<0x4E>(v);
    v += dpp_mov_f<0x141>(v);
    v += dpp_mov_f<0x128>(v);   // row_ror:8 == xor 8 within 16-lane row
    return v;
}
static __device__ __forceinline__ float red4f(float v) {
    v += dpp_mov_f<0xB1>(v);
    v += dpp_mov_f<0x4E>(v);
    return v;
}
static __device__ __forceinline__ float red2f(float v) {
    return v + dpp_mov_f<0xB1>(v);
}

extern "C" __global__ void __launch_bounds__(NT, 1)
ncde_solve(const float* __restrict__ x,
           const float* __restrict__ ic_w1, const float* __restrict__ ic_b1,
           const float* __restrict__ ic_w2, const float* __restrict__ ic_b2,
           const float* __restrict__ ic_w3, const float* __restrict__ ic_b3,
           const float* __restrict__ vf_w1, const float* __restrict__ vf_b1,
           const float* __restrict__ vf_w2, const float* __restrict__ vf_b2,
           const float* __restrict__ vf_w3, const float* __restrict__ vf_b3,
           const float* __restrict__ ro_w,  const float* __restrict__ ro_b,
           float* __restrict__ out)
{
    __shared__ double smd[D_TOTAL];
    __shared__ __align__(16) float smf[F_TOTAL];

    const int t = threadIdx.x;
    const int b = blockIdx.x;
    const float* xb = x + (size_t)b * (257 * 8);

    const int o8 = t >> 3, p8 = t & 7;      // P1/P2
    const int o16 = t >> 4, p16 = t & 15;   // P5/P6 (rows o16, o16+64)
    const int m = t >> 2, q = t & 3;        // P3/P7 (rows 2m,2m+1)
    const int aT = t >> 7;                  // tangent index

    // ---- weights in f32 registers ----
    float w1f[8];    // P1: row o8, cols [8p8, 8p8+8)
    {
        const float4* s4 = reinterpret_cast<const float4*>(vf_w1 + o8 * 64 + 8 * p8);
        float4 v0 = s4[0], v1 = s4[1];
        w1f[0] = v0.x; w1f[1] = v0.y; w1f[2] = v0.z; w1f[3] = v0.w;
        w1f[4] = v1.x; w1f[5] = v1.y; w1f[6] = v1.z; w1f[7] = v1.w;
    }
    float w2f[16];   // P2: row o8, cols [16p8, 16p8+16)
    {
        const float4* s4 = reinterpret_cast<const float4*>(vf_w2 + o8 * 128 + 16 * p8);
        #pragma unroll
        for (int jj = 0; jj < 4; ++jj) {
            float4 v = s4[jj];
            w2f[4 * jj] = v.x; w2f[4 * jj + 1] = v.y;
            w2f[4 * jj + 2] = v.z; w2f[4 * jj + 3] = v.w;
        }
    }
    float w1u[2][4]; // P5: rows o16,o16+64, cols [4p16,4p16+4)
    {
        float4 a = *reinterpret_cast<const float4*>(vf_w1 + o16 * 64 + 4 * p16);
        float4 c = *reinterpret_cast<const float4*>(vf_w1 + (o16 + 64) * 64 + 4 * p16);
        w1u[0][0] = a.x; w1u[0][1] = a.y; w1u[0][2] = a.z; w1u[0][3] = a.w;
        w1u[1][0] = c.x; w1u[1][1] = c.y; w1u[1][2] = c.z; w1u[1][3] = c.w;
    }
    float w2u[2][8]; // P6: rows o16,o16+64, cols [8p16,8p16+8)
    {
        const float4* sa = reinterpret_cast<const float4*>(vf_w2 + o16 * 128 + 8 * p16);
        const float4* sb = reinterpret_cast<const float4*>(vf_w2 + (o16 + 64) * 128 + 8 * p16);
        float4 a0 = sa[0], a1 = sa[1], c0 = sb[0], c1 = sb[1];
        w2u[0][0] = a0.x; w2u[0][1] = a0.y; w2u[0][2] = a0.z; w2u[0][3] = a0.w;
        w2u[0][4] = a1.x; w2u[0][5] = a1.y; w2u[0][6] = a1.z; w2u[0][7] = a1.w;
        w2u[1][0] = c0.x; w2u[1][1] = c0.y; w2u[1][2] = c0.z; w2u[1][3] = c0.w;
        w2u[1][4] = c1.x; w2u[1][5] = c1.y; w2u[1][6] = c1.z; w2u[1][7] = c1.w;
    }
    float w3a[32], w3b[32]; // P3/P7: rows 2m,2m+1, cols [32q,32q+32)
    {
        const float4* sa = reinterpret_cast<const float4*>(vf_w3 + (size_t)(2 * m) * 128 + 32 * q);
        const float4* sb = reinterpret_cast<const float4*>(vf_w3 + (size_t)(2 * m + 1) * 128 + 32 * q);
        #pragma unroll
        for (int jj = 0; jj < 8; ++jj) {
            float4 va = sa[jj], vb = sb[jj];
            w3a[4 * jj] = va.x; w3a[4 * jj + 1] = va.y; w3a[4 * jj + 2] = va.z; w3a[4 * jj + 3] = va.w;
            w3b[4 * jj] = vb.x; w3b[4 * jj + 1] = vb.y; w3b[4 * jj + 2] = vb.z; w3b[4 * jj + 3] = vb.w;
        }
    }
    const float b1o = vf_b1[o8];
    const float b2o = vf_b2[o8];
    const float b3a = vf_b3[2 * m];
    const float b3b = vf_b3[2 * m + 1];

    // ==== init: X0 + logsigs (f64) ====
    if (t < 8) smd[D_X0 + t] = (double)xb[t];
    if (t < 16) {
        const float* xr = xb + t * 16 * 8;
        double cum[8], area[28], prev[8];
        #pragma unroll
        for (int i = 0; i < 8; ++i) { cum[i] = 0.0; prev[i] = (double)xr[i]; }
        #pragma unroll
        for (int u = 0; u < 28; ++u) area[u] = 0.0;
        for (int k = 1; k <= 16; ++k) {
            double dx[8];
            #pragma unroll
            for (int i = 0; i < 8; ++i) {
                double c = (double)xr[k * 8 + i];
                dx[i] = c - prev[i];
                prev[i] = c;
            }
            #pragma unroll
            for (int i = 0; i < 7; ++i) {
                #pragma unroll
                for (int j = i + 1; j < 8; ++j) {
                    int u = 7 * i - (i * (i - 1)) / 2 + (j - i - 1);
                    area[u] += 0.5 * (cum[i] * dx[j] - cum[j] * dx[i]);
                }
            }
            #pragma unroll
            for (int i = 0; i < 8; ++i) cum[i] += dx[i];
        }
        #pragma unroll
        for (int i = 0; i < 8; ++i) smd[D_VSIG + t * 36 + i] = cum[i];
        #pragma unroll
        for (int u = 0; u < 28; ++u) smd[D_VSIG + t * 36 + 8 + u] = area[u];
    }
    __syncthreads();

    // ==== ic MLP (f64; scratch in D_T3) ====
    if (t < 128) {
        double acc = (double)ic_b1[t];
        #pragma unroll
        for (int e = 0; e < 8; ++e) acc += (double)ic_w1[t * 8 + e] * smd[D_X0 + e];
        double d;
        smd[D_T3 + t] = lipswish_d(acc, &d);
    }
    __syncthreads();
    if (t < 128) {
        const float4* wr = reinterpret_cast<const float4*>(ic_w2 + t * 128);
        double a0 = 0.0, a1 = 0.0, a2 = 0.0, a3 = 0.0;
        #pragma unroll
        for (int k = 0; k < 32; ++k) {
            float4 wv = wr[k];
            double2 h0 = *reinterpret_cast<const double2*>(&smd[D_T3 + 4 * k]);
            double2 h1 = *reinterpret_cast<const double2*>(&smd[D_T3 + 4 * k + 2]);
            a0 += (double)wv.x * h0.x; a1 += (double)wv.y * h0.y;
            a2 += (double)wv.z * h1.x; a3 += (double)wv.w * h1.y;
        }
        double d;
        smd[D_T3 + 128 + t] = lipswish_d((double)ic_b2[t] + (a0 + a2) + (a1 + a3), &d);
    }
    __syncthreads();
    if (t < 64) {
        const float4* wr = reinterpret_cast<const float4*>(ic_w3 + t * 128);
        double a0 = 0.0, a1 = 0.0, a2 = 0.0, a3 = 0.0;
        #pragma unroll
        for (int k = 0; k < 32; ++k) {
            float4 wv = wr[k];
            double2 h0 = *reinterpret_cast<const double2*>(&smd[D_T3 + 128 + 4 * k]);
            double2 h1 = *reinterpret_cast<const double2*>(&smd[D_T3 + 128 + 4 * k + 2]);
            a0 += (double)wv.x * h0.x; a1 += (double)wv.y * h0.y;
            a2 += (double)wv.z * h1.x; a3 += (double)wv.w * h1.y;
        }
        double y0 = (double)ic_b3[t] + (a0 + a2) + (a1 + a3);
        smd[D_YCUR + t] = y0;
        smd[D_HID + t]  = y0;
        smf[F_YB + t + 4 * (t >> 3)] = (float)y0;
        int a = t >> 3, bb = t & 7;
        double cv = 0.0;
        if (a != bb) {
            int i = a < bb ? a : bb;
            int j = a < bb ? bb : a;
            int pidx = 7 * i - (i * (i - 1)) / 2 + (j - i - 1);
            double vv = smd[D_VSIG + 8 + pidx];
            cv = (a > bb) ? vv : -vv;
        }
        smf[F_CM + t] = (float)cv;
    }
    __syncthreads();

    // ==== RK4 scan ====
    for (int w = 0; w < 16; ++w) {
        for (int stage = 0; stage < 4; ++stage) {
            // ---- P1: L1 f32 ----
            {
                float4 y0 = *reinterpret_cast<const float4*>(&smf[F_YB + 12 * p8]);
                float4 y1 = *reinterpret_cast<const float4*>(&smf[F_YB + 12 * p8 + 4]);
                float acc = w1f[0] * y0.x + w1f[1] * y0.y + w1f[2] * y0.z + w1f[3] * y0.w
                          + w1f[4] * y1.x + w1f[5] * y1.y + w1f[6] * y1.z + w1f[7] * y1.w;
                acc = red8f(acc);
                if (p8 == 0) {
                    float d;
                    smf[F_H1 + o8 + 4 * (o8 >> 4)] = lipswish_f(acc + b1o, &d);
                    smf[F_D1 + o8] = d;
                }
            }
            __syncthreads();
            // ---- P2: L2 f32 ----
            {
                const float4* hv = reinterpret_cast<const float4*>(&smf[F_H1 + 20 * p8]);
                float4 h0 = hv[0], h1 = hv[1], h2 = hv[2], h3 = hv[3];
                float a0 = w2f[0] * h0.x + w2f[1] * h0.y + w2f[2] * h0.z + w2f[3] * h0.w
                         + w2f[4] * h1.x + w2f[5] * h1.y + w2f[6] * h1.z + w2f[7] * h1.w;
                float a1 = w2f[8] * h2.x + w2f[9] * h2.y + w2f[10] * h2.z + w2f[11] * h2.w
                         + w2f[12] * h3.x + w2f[13] * h3.y + w2f[14] * h3.z + w2f[15] * h3.w;
                float acc = red8f(a0 + a1);
                if (p8 == 0) {
                    float d;
                    smf[F_H2 + o8 + 4 * (o8 >> 4)] = lipswish_f(acc + b2o, &d);
                    smf[F_D2 + o8] = d;
                }
            }
            __syncthreads();
            // ---- P3: L3 f32, dual-row q4 ----
            float F0 = 0.0f, F1 = 0.0f;
            {
                float a0 = 0.0f, a1 = 0.0f;
                #pragma unroll
                for (int jj = 0; jj < 8; ++jj) {
                    float4 hv = *reinterpret_cast<const float4*>(
                        &smf[F_H2 + 40 * q + 4 * jj + 4 * (jj >> 2)]);
                    a0 += w3a[4 * jj] * hv.x + w3a[4 * jj + 1] * hv.y
                        + w3a[4 * jj + 2] * hv.z + w3a[4 * jj + 3] * hv.w;
                    a1 += w3b[4 * jj] * hv.x + w3b[4 * jj + 1] * hv.y
                        + w3b[4 * jj + 2] * hv.z + w3b[4 * jj + 3] * hv.w;
                }
                a0 = red4f(a0);
                a1 = red4f(a1);
                if (q == 0) {
                    F0 = tanhf(a0 + b3a);
                    F1 = tanhf(a1 + b3b);
                    float2 fv; fv.x = F0; fv.y = F1;
                    *reinterpret_cast<float2*>(&smf[F_FB + 2 * m]) = fv;
                }
            }
            __syncthreads();
            // ---- P4: WM f32 ----
            {
                int kw = t & 1, ew = (t >> 1) & 63;
                float s = 0.0f;
                #pragma unroll
                for (int i = 0; i < 4; ++i) {
                    int bb = 4 * kw + i;
                    s += smf[F_CM + aT * 8 + bb] * smf[F_FB + bb * 64 + ew];
                }
                s = red2f(s);
                if (kw == 0) smf[F_WM + aT * 64 + ew] = s;
            }
            __syncthreads();
            // ---- P5: U1 f32, 2 rows/thread, 16-wide K ----
            {
                float d1a = smf[F_D1 + o16], d1b = smf[F_D1 + o16 + 64];
                int ob = F_U1 + o16 + 4 * (o16 >> 4);
                #pragma unroll
                for (int a = 0; a < 8; ++a) {
                    float4 mv = *reinterpret_cast<const float4*>(&smf[F_WM + a * 64 + 4 * p16]);
                    float a0 = w1u[0][0] * mv.x + w1u[0][1] * mv.y + w1u[0][2] * mv.z + w1u[0][3] * mv.w;
                    float a1 = w1u[1][0] * mv.x + w1u[1][1] * mv.y + w1u[1][2] * mv.z + w1u[1][3] * mv.w;
                    a0 = red16f(a0);
                    a1 = red16f(a1);
                    if (p16 == 0) {
                        smf[ob + a * 160]      = a0 * d1a;
                        smf[ob + a * 160 + 80] = a1 * d1b;
                    }
                }
            }
            __syncthreads();
            // ---- P6: U2 f32, 2 rows/thread, 16-wide K ----
            {
                float d2a = smf[F_D2 + o16], d2b = smf[F_D2 + o16 + 64];
                int ib = 8 * p16 + 4 * (p16 >> 1);
                int ob = F_U2 + o16 + 4 * (o16 >> 4);
                #pragma unroll
                for (int a = 0; a < 8; ++a) {
                    float4 u0 = *reinterpret_cast<const float4*>(&smf[F_U1 + a * 160 + ib]);
                    float4 u1 = *reinterpret_cast<const float4*>(&smf[F_U1 + a * 160 + ib + 4]);
                    float a0 = w2u[0][0] * u0.x + w2u[0][1] * u0.y + w2u[0][2] * u0.z + w2u[0][3] * u0.w
                             + w2u[0][4] * u1.x + w2u[0][5] * u1.y + w2u[0][6] * u1.z + w2u[0][7] * u1.w;
                    float a1 = w2u[1][0] * u0.x + w2u[1][1] * u0.y + w2u[1][2] * u0.z + w2u[1][3] * u0.w
                             + w2u[1][4] * u1.x + w2u[1][5] * u1.y + w2u[1][6] * u1.z + w2u[1][7] * u1.w;
                    a0 = red16f(a0);
                    a1 = red16f(a1);
                    if (p16 == 0) {
                        smf[ob + a * 160]      = a0 * d2a;
                        smf[ob + a * 160 + 80] = a1 * d2b;
                    }
                }
            }
            __syncthreads();
            // ---- P7: T3, dual-row q4 (f32 dot, f64 finish) ----
            {
                float a0 = 0.0f, a1 = 0.0f;
                #pragma unroll
                for (int jj = 0; jj < 8; ++jj) {
                    float4 uv = *reinterpret_cast<const float4*>(
                        &smf[F_U2 + aT * 160 + 40 * q + 4 * jj + 4 * (jj >> 2)]);
                    a0 += w3a[4 * jj] * uv.x + w3a[4 * jj + 1] * uv.y
                        + w3a[4 * jj + 2] * uv.z + w3a[4 * jj + 3] * uv.w;
                    a1 += w3b[4 * jj] * uv.x + w3b[4 * jj + 1] * uv.y
                        + w3b[4 * jj + 2] * uv.z + w3b[4 * jj + 3] * uv.w;
                }
                a0 = red4f(a0);
                a1 = red4f(a1);
                if (q == 0) {
                    double va = smd[D_VSIG + w * 36 + aT];
                    double2 tv;
                    tv.x = va * (double)F0 + (1.0 - (double)F0 * F0) * (double)a0;
                    tv.y = va * (double)F1 + (1.0 - (double)F1 * F1) * (double)a1;
                    *reinterpret_cast<double2*>(&smd[D_T3 + 2 * m]) = tv;
                }
            }
            __syncthreads();
            // ---- P8: combine + RK4 glue f64 (+ next CMAT) ----
            if (t < 64) {
                double g = 0.0;
                #pragma unroll
                for (int a = 0; a < 8; ++a) g += smd[D_T3 + a * 64 + t];
                double y = smd[D_YCUR + t];
                int yp = F_YB + t + 4 * (t >> 3);
                if (stage == 0)      { smd[D_KACC + t] = g;        smf[yp] = (float)(y + 0.5 * g); }
                else if (stage == 1) { smd[D_KACC + t] += 2.0 * g; smf[yp] = (float)(y + 0.5 * g); }
                else if (stage == 2) { smd[D_KACC + t] += 2.0 * g; smf[yp] = (float)(y + g); }
                else {
                    double yn = y + (smd[D_KACC + t] + g) * (1.0 / 6.0);
                    smd[D_YCUR + t] = yn;
                    smf[yp] = (float)yn;
                    smd[D_HID + (w + 1) * 64 + t] = yn;
                }
            } else if (t < 128 && stage == 3 && w < 15) {
                int idx = t - 64;
                int a = idx >> 3, bb = idx & 7;
                double cv = 0.0;
                if (a != bb) {
                    int i = a < bb ? a : bb;
                    int j = a < bb ? bb : a;
                    int pidx = 7 * i - (i * (i - 1)) / 2 + (j - i - 1);
                    double vv = smd[D_VSIG + (w + 1) * 36 + 8 + pidx];
                    cv = (a > bb) ? vv : -vv;
                }
                smf[F_CM + idx] = (float)cv;
            }
            __syncthreads();
        }
    }

    // ==== readout (f64) ====
    for (int idx = t; idx < 544; idx += NT) {
        int s = idx >> 5, oo = idx & 31;
        double acc = (double)ro_b[oo];
        const float* wr = ro_w + oo * 64;
        const double* hr = &smd[D_HID + s * 64];
        #pragma unroll
        for (int d = 0; d < 64; ++d) acc += (double)wr[d] * hr[d];
        out[(size_t)b * 544 + idx] = (float)acc;
    }
}

extern "C" void kernel_launch(void* const* d_in, const int* in_sizes, int n_in,
                              void* d_out, int out_size, void* d_ws, size_t ws_size,
                              hipStream_t stream) {
    const float* x     = (const float*)d_in[0];
    const float* ic_w1 = (const float*)d_in[1];
    const float* ic_b1 = (const float*)d_in[2];
    const float* ic_w2 = (const float*)d_in[3];
    const float* ic_b2 = (const float*)d_in[4];
    const float* ic_w3 = (const float*)d_in[5];
    const float* ic_b3 = (const float*)d_in[6];
    const float* vf_w1 = (const float*)d_in[7];
    const float* vf_b1 = (const float*)d_in[8];
    const float* vf_w2 = (const float*)d_in[9];
    const float* vf_b2 = (const float*)d_in[10];
    const float* vf_w3 = (const float*)d_in[11];
    const float* vf_b3 = (const float*)d_in[12];
    const float* ro_w  = (const float*)d_in[13];
    const float* ro_b  = (const float*)d_in[14];
    float* out = (float*)d_out;

    int B = in_sizes[0] / (257 * 8);
    hipLaunchKernelGGL(ncde_solve, dim3(B), dim3(NT), 0, stream,
                       x, ic_w1, ic_b1, ic_w2, ic_b2, ic_w3, ic_b3,
                       vf_w1, vf_b1, vf_w2, vf_b2, vf_w3, vf_b3, ro_w, ro_b, out);
}